// Round 17
// baseline (379.994 us; speedup 1.0000x reference)
//
#include <hip/hip_runtime.h>

#define Bc 8
#define Nc 512
#define INc 64
#define Hc 128
#define Atc 32
#define REDc 32
#define OUTc 3
#define Lc 3
#define MNc (Bc * Nc)
#define KT 32
#define WPAD 36   // row stride 144B: conflict-free strided b128 reads

__device__ __forceinline__ float tanh_fast(float x) {
    float e = __expf(2.f * x);
    return 1.f - 2.f * __builtin_amdgcn_rcpf(e + 1.f);
}

// Prologue: blocks [0, MN) build CSR; blocks [MN, MN+MN/8) run embed GEMM.
__global__ __launch_bounds__(256) void prologue(
        const float* __restrict__ A, const float* __restrict__ Acg,
        int* __restrict__ idxA, int* __restrict__ idxC,
        int* __restrict__ cntA, int* __restrict__ cntC,
        const float* __restrict__ X, const float* __restrict__ embed_w,
        const float* __restrict__ embed_b, float* __restrict__ Xh) {
    __shared__ int cA, cC;
    __shared__ float xs[8 * INc];
    int blk = blockIdx.x;
    int t = threadIdx.x;
    if (blk < MNc) {
        if (t == 0) { cA = 0; cC = 0; }
        __syncthreads();
        if (t < 128) {
            int h = t;
            int* ia = idxA + (size_t)blk * Nc;
            int* ic = idxC + (size_t)blk * Nc;
            float4 a4 = ((const float4*)(A + (size_t)blk * Nc))[h];
            if (a4.x != 0.f) ia[atomicAdd(&cA, 1)] = 4 * h;
            if (a4.y != 0.f) ia[atomicAdd(&cA, 1)] = 4 * h + 1;
            if (a4.z != 0.f) ia[atomicAdd(&cA, 1)] = 4 * h + 2;
            if (a4.w != 0.f) ia[atomicAdd(&cA, 1)] = 4 * h + 3;
            float4 c4 = ((const float4*)(Acg + (size_t)blk * Nc))[h];
            if (c4.x != 0.f) ic[atomicAdd(&cC, 1)] = 4 * h;
            if (c4.y != 0.f) ic[atomicAdd(&cC, 1)] = 4 * h + 1;
            if (c4.z != 0.f) ic[atomicAdd(&cC, 1)] = 4 * h + 2;
            if (c4.w != 0.f) ic[atomicAdd(&cC, 1)] = 4 * h + 3;
        }
        __syncthreads();
        if (t == 0) { cntA[blk] = cA; cntC[blk] = cC; }
    } else {
        int m0 = (blk - MNc) * 8;
        if (t < 128) ((float4*)xs)[t] = ((const float4*)(X + (size_t)m0 * INc))[t];
        __syncthreads();
        int n = t & 127, grp = t >> 7;
        float bv = embed_b[n];
        float acc[4];
#pragma unroll
        for (int r = 0; r < 4; ++r) acc[r] = bv;
        const float* w = embed_w + (size_t)n * INc;
        for (int k = 0; k < INc; k += 4) {
            float4 wv = *(const float4*)(w + k);
#pragma unroll
            for (int r = 0; r < 4; ++r) {
                float4 xv = *(const float4*)(xs + (grp * 4 + r) * INc + k);
                acc[r] = fmaf(xv.x, wv.x, acc[r]); acc[r] = fmaf(xv.y, wv.y, acc[r]);
                acc[r] = fmaf(xv.z, wv.z, acc[r]); acc[r] = fmaf(xv.w, wv.w, acc[r]);
            }
        }
#pragma unroll
        for (int r = 0; r < 4; ++r)
            Xh[(size_t)(m0 + grp * 4 + r) * Hc + n] = acc[r];
    }
}

// Dual SpMM from precomputed CSR. WIDE grid — gather latency hidden by TLP.
__global__ __launch_bounds__(128) void spmm_pre(
        const int* __restrict__ idxA, const int* __restrict__ idxC,
        const int* __restrict__ cntA, const int* __restrict__ cntC,
        const float* __restrict__ X, const float* __restrict__ eA,
        const float* __restrict__ eC, float* __restrict__ T1, float* __restrict__ T2) {
    int bi = blockIdx.x;
    int b = bi >> 9;
    int h = threadIdx.x;
    __shared__ int ias[Nc], ics[Nc];
    int nA = cntA[bi], nC = cntC[bi];
    for (int q = h; q < nA; q += 128) ias[q] = idxA[(size_t)bi * Nc + q];
    for (int q = h; q < nC; q += 128) ics[q] = idxC[(size_t)bi * Nc + q];
    __syncthreads();
    const float* Xb = X + (size_t)b * Nc * Hc;
    float a1 = 0.f, a2 = 0.f;
    for (int q = 0; q < nA; ++q) a1 += Xb[(size_t)ias[q] * Hc + h];
    for (int q = 0; q < nC; ++q) a2 += Xb[(size_t)ics[q] * Hc + h];
    size_t o = (size_t)bi * Hc + h;
    float xv = X[o];
    T1[o] = (1.f + eA[0]) * xv + a1;
    T2[o] = (1.f + eC[0]) * xv + a2;
}

// Stage one KT-wide weight tile into Ws[128][WPAD] (coalesced global reads).
__device__ __forceinline__ void stage_wtile(
        const float* __restrict__ W, int kt, float* Ws, int t) {
#pragma unroll
    for (int i = 0; i < 4; ++i) {
        int idx = t + i * 256;
        int row = idx >> 3, c4 = idx & 7;
        float4 v = *(const float4*)(W + (size_t)row * Hc + kt + c4 * 4);
        *(float4*)(Ws + row * WPAD + c4 * 4) = v;
    }
}

// Topo GIN, register-tiled: 32 rows/block, grid 128. Shared W on T1/T2
// (one Ws staging feeds both accumulators). Epilogue: Xp = Xh +
// tanh(relu(g1)*th0) + tanh(relu(g2)*th1), theta indexed per output col.
__global__ __launch_bounds__(256) void topo_gemm4(
        const float* __restrict__ T1, const float* __restrict__ T2,
        const float* __restrict__ W, const float* __restrict__ bias,
        const float* __restrict__ Xh, const float* __restrict__ theta,
        float* __restrict__ Xp) {
    __shared__ float xs1[32 * Hc];    // 16 KB
    __shared__ float xs2[32 * Hc];    // 16 KB
    __shared__ float Ws[Hc * WPAD];   // 18 KB
    int m0 = blockIdx.x * 32;
    int t = threadIdx.x;
    {
        const float4* s1 = (const float4*)(T1 + (size_t)m0 * Hc);
        const float4* s2 = (const float4*)(T2 + (size_t)m0 * Hc);
#pragma unroll
        for (int i = 0; i < 4; ++i) {
            ((float4*)xs1)[t + i * 256] = s1[t + i * 256];
            ((float4*)xs2)[t + i * 256] = s2[t + i * 256];
        }
    }
    int cg = t & 31, rg = t >> 5;
    float ac1[4][4], ac2[4][4];
#pragma unroll
    for (int r = 0; r < 4; ++r)
#pragma unroll
        for (int c = 0; c < 4; ++c) { ac1[r][c] = 0.f; ac2[r][c] = 0.f; }
#pragma unroll 1
    for (int kt = 0; kt < Hc; kt += KT) {
        __syncthreads();
        stage_wtile(W, kt, Ws, t);
        __syncthreads();
#pragma unroll
        for (int k = 0; k < KT; k += 4) {
            float4 x1[4], x2[4], wv[4];
#pragma unroll
            for (int r = 0; r < 4; ++r) {
                x1[r] = *(const float4*)(xs1 + (rg * 4 + r) * Hc + kt + k);
                x2[r] = *(const float4*)(xs2 + (rg * 4 + r) * Hc + kt + k);
            }
#pragma unroll
            for (int c = 0; c < 4; ++c)
                wv[c] = *(const float4*)(Ws + (cg + 32 * c) * WPAD + k);
#pragma unroll
            for (int r = 0; r < 4; ++r)
#pragma unroll
                for (int c = 0; c < 4; ++c) {
                    ac1[r][c] = fmaf(x1[r].x, wv[c].x, ac1[r][c]);
                    ac1[r][c] = fmaf(x1[r].y, wv[c].y, ac1[r][c]);
                    ac1[r][c] = fmaf(x1[r].z, wv[c].z, ac1[r][c]);
                    ac1[r][c] = fmaf(x1[r].w, wv[c].w, ac1[r][c]);
                    ac2[r][c] = fmaf(x2[r].x, wv[c].x, ac2[r][c]);
                    ac2[r][c] = fmaf(x2[r].y, wv[c].y, ac2[r][c]);
                    ac2[r][c] = fmaf(x2[r].z, wv[c].z, ac2[r][c]);
                    ac2[r][c] = fmaf(x2[r].w, wv[c].w, ac2[r][c]);
                }
        }
    }
#pragma unroll
    for (int c = 0; c < 4; ++c) {
        int n = cg + 32 * c;
        float bv = bias[n];
        float th0 = theta[2 * n], th1 = theta[2 * n + 1];
#pragma unroll
        for (int r = 0; r < 4; ++r) {
            size_t o = (size_t)(m0 + rg * 4 + r) * Hc + n;
            float g1 = fmaxf(ac1[r][c] + bv, 0.f);
            float g2 = fmaxf(ac2[r][c] + bv, 0.f);
            Xp[o] = Xh[o] + tanh_fast(g1 * th0) + tanh_fast(g2 * th1);
        }
    }
}

// Per-layer GEMMs, register-tiled (r16, frozen): 4 roles x 128 blocks.
__global__ __launch_bounds__(256) void layer_gemm4(
        const float* __restrict__ T1, const float* __restrict__ T2,
        const float* __restrict__ W1, const float* __restrict__ b1,
        const float* __restrict__ W2, const float* __restrict__ b2,
        const float* __restrict__ Xp, const float* __restrict__ wy_w,
        const float* __restrict__ wy_b, const float* __restrict__ wo,
        const float* __restrict__ w1a, float* __restrict__ GS1,
        float* __restrict__ GS2, float* __restrict__ Xy,
        float* __restrict__ hov, float* __restrict__ h1v) {
    __shared__ float xs[32 * Hc];     // 16 KB
    __shared__ float Ws[Hc * WPAD];   // 18 KB
    int blk = blockIdx.x;
    int role = blk >> 7;
    int m0 = (blk & 127) * 32;
    int t = threadIdx.x;
    const float* xsrc = (role == 0) ? T1 : (role == 1) ? T2 : Xp;
    {
        const float4* src = (const float4*)(xsrc + (size_t)m0 * Hc);
#pragma unroll
        for (int i = 0; i < 4; ++i) ((float4*)xs)[t + i * 256] = src[t + i * 256];
    }
    if (role == 3) {
        __syncthreads();
        int n2 = t & 63, g2 = t >> 6;
        const float* w = (n2 < 32) ? (wo + (size_t)n2 * Hc) : (w1a + (size_t)(n2 - 32) * Hc);
        float acc[8];
#pragma unroll
        for (int r = 0; r < 8; ++r) acc[r] = 0.f;
        for (int k = 0; k < Hc; k += 4) {
            float4 wv = *(const float4*)(w + k);
#pragma unroll
            for (int r = 0; r < 8; ++r) {
                float4 xv = *(const float4*)(xs + (g2 * 8 + r) * Hc + k);
                acc[r] = fmaf(xv.x, wv.x, acc[r]); acc[r] = fmaf(xv.y, wv.y, acc[r]);
                acc[r] = fmaf(xv.z, wv.z, acc[r]); acc[r] = fmaf(xv.w, wv.w, acc[r]);
            }
        }
#pragma unroll
        for (int r = 0; r < 8; ++r) {
            int m = m0 + g2 * 8 + r;
            float v = tanh_fast(acc[r]);
            if (n2 < 32) hov[(size_t)m * Atc + n2] = v;
            else h1v[(size_t)m * Atc + (n2 - 32)] = v;
        }
        return;
    }
    const float* W = (role == 0) ? W1 : (role == 1) ? W2 : wy_w;
    const float* bias = (role == 0) ? b1 : (role == 1) ? b2 : wy_b;
    int cg = t & 31, rg = t >> 5;
    float acc[4][4];
#pragma unroll
    for (int r = 0; r < 4; ++r)
#pragma unroll
        for (int c = 0; c < 4; ++c) acc[r][c] = 0.f;
#pragma unroll 1
    for (int kt = 0; kt < Hc; kt += KT) {
        __syncthreads();
        stage_wtile(W, kt, Ws, t);
        __syncthreads();
#pragma unroll
        for (int k = 0; k < KT; k += 4) {
            float4 xv[4], wv[4];
#pragma unroll
            for (int r = 0; r < 4; ++r)
                xv[r] = *(const float4*)(xs + (rg * 4 + r) * Hc + kt + k);
#pragma unroll
            for (int c = 0; c < 4; ++c)
                wv[c] = *(const float4*)(Ws + (cg + 32 * c) * WPAD + k);
#pragma unroll
            for (int r = 0; r < 4; ++r)
#pragma unroll
                for (int c = 0; c < 4; ++c) {
                    acc[r][c] = fmaf(xv[r].x, wv[c].x, acc[r][c]);
                    acc[r][c] = fmaf(xv[r].y, wv[c].y, acc[r][c]);
                    acc[r][c] = fmaf(xv[r].z, wv[c].z, acc[r][c]);
                    acc[r][c] = fmaf(xv[r].w, wv[c].w, acc[r][c]);
                }
        }
    }
    float bvv[4];
#pragma unroll
    for (int c = 0; c < 4; ++c) bvv[c] = bias[cg + 32 * c];
    if (role == 0) {
#pragma unroll
        for (int r = 0; r < 4; ++r)
#pragma unroll
            for (int c = 0; c < 4; ++c)
                GS1[(size_t)(m0 + rg * 4 + r) * Hc + cg + 32 * c] =
                    fmaxf(acc[r][c] + bvv[c], 0.f);
    } else if (role == 1) {
#pragma unroll
        for (int r = 0; r < 4; ++r)
#pragma unroll
            for (int c = 0; c < 4; ++c)
                GS2[(size_t)(m0 + rg * 4 + r) * Hc + cg + 32 * c] =
                    fmaxf(acc[r][c] + bvv[c], 0.f);
    } else {
#pragma unroll
        for (int r = 0; r < 4; ++r)
#pragma unroll
            for (int c = 0; c < 4; ++c)
                Xy[(size_t)(m0 + rg * 4 + r) * Hc + cg + 32 * c] = acc[r][c] + bvv[c];
    }
}

// Flash-style partial attention (frozen from r13/r16).
__global__ __launch_bounds__(256, 4) void attn_part(
        const float* __restrict__ ta, const float* __restrict__ tb,
        const float* __restrict__ wphi, const float* __restrict__ Xy,
        float* __restrict__ Pp, float* __restrict__ ctxp, float* __restrict__ wsp) {
    int blk = blockIdx.x;
    int b = blk >> 8;
    int r6 = (blk >> 2) & 63;
    int js = blk & 3;
    int i0 = r6 * 8;
    int t = threadIdx.x;
    __shared__ float als[8 * 128];
    __shared__ float4 red4[1024];
    __shared__ float tas[8 * 32];
    tas[t] = ta[((size_t)b * Nc + i0) * 32 + t];
    __syncthreads();
    {
        int i = t >> 5;
        int kq = t & 3;
        int jl = (t >> 2) & 7;
        float4 wp0 = ((const float4*)wphi)[kq * 2];
        float4 wp1 = ((const float4*)wphi)[kq * 2 + 1];
        float4 ta0 = *(const float4*)(tas + i * 32 + kq * 8);
        float4 ta1 = *(const float4*)(tas + i * 32 + kq * 8 + 4);
        const float* tbb = tb + ((size_t)b * Nc + js * 128) * 32;
        const float4* p = (const float4*)(tbb + (size_t)jl * 32 + kq * 8);
        float4 c0a = p[0], c0b = p[1];
        float4 c1a = p[64], c1b = p[65];
        float ca[8];
#pragma unroll
        for (int q = 0; q < 8; ++q) ca[q] = 0.f;
        float wsum = 0.f;
#pragma unroll 4
        for (int jj = 0; jj < 16; ++jj) {
            float4 ha = c0a, hb = c0b;
            c0a = c1a; c0b = c1b;
            if (jj < 14) { c1a = p[(jj + 2) * 64]; c1b = p[(jj + 2) * 64 + 1]; }
            float e0 = (ta0.x + ha.x) * __builtin_amdgcn_rcpf(fmaf(ta0.x, ha.x, 1.f));
            float e1 = (ta0.y + ha.y) * __builtin_amdgcn_rcpf(fmaf(ta0.y, ha.y, 1.f));
            float e2 = (ta0.z + ha.z) * __builtin_amdgcn_rcpf(fmaf(ta0.z, ha.z, 1.f));
            float e3 = (ta0.w + ha.w) * __builtin_amdgcn_rcpf(fmaf(ta0.w, ha.w, 1.f));
            float e4 = (ta1.x + hb.x) * __builtin_amdgcn_rcpf(fmaf(ta1.x, hb.x, 1.f));
            float e5 = (ta1.y + hb.y) * __builtin_amdgcn_rcpf(fmaf(ta1.y, hb.y, 1.f));
            float e6 = (ta1.z + hb.z) * __builtin_amdgcn_rcpf(fmaf(ta1.z, hb.z, 1.f));
            float e7 = (ta1.w + hb.w) * __builtin_amdgcn_rcpf(fmaf(ta1.w, hb.w, 1.f));
            float s01 = fmaf(e1, wp0.y, e0 * wp0.x);
            float s23 = fmaf(e3, wp0.w, e2 * wp0.z);
            float s45 = fmaf(e5, wp1.y, e4 * wp1.x);
            float s67 = fmaf(e7, wp1.w, e6 * wp1.z);
            float sc = (s01 + s23) + (s45 + s67);
            sc += __shfl_xor(sc, 1);
            sc += __shfl_xor(sc, 2);
            float w = __expf(sc);
            if (kq == 0) als[i * 128 + jj * 8 + jl] = w;
            wsum += w;
            ca[0] = fmaf(w, e0, ca[0]);
            ca[1] = fmaf(w, e1, ca[1]);
            ca[2] = fmaf(w, e2, ca[2]);
            ca[3] = fmaf(w, e3, ca[3]);
            ca[4] = fmaf(w, e4, ca[4]);
            ca[5] = fmaf(w, e5, ca[5]);
            ca[6] = fmaf(w, e6, ca[6]);
            ca[7] = fmaf(w, e7, ca[7]);
        }
#pragma unroll
        for (int o = 16; o > 0; o >>= 1) wsum += __shfl_xor(wsum, o);
        if ((t & 31) == 0) wsp[(size_t)js * MNc + (size_t)b * Nc + i0 + i] = wsum;
#pragma unroll
        for (int q = 0; q < 8; ++q) {
            ca[q] += __shfl_xor(ca[q], 4);
            ca[q] += __shfl_xor(ca[q], 8);
            ca[q] += __shfl_xor(ca[q], 16);
        }
        if (jl == 0) {
            float* cp = ctxp + ((size_t)js * MNc + (size_t)b * Nc + i0 + i) * 32 + kq * 8;
#pragma unroll
            for (int q = 0; q < 8; ++q) cp[q] = ca[q];
        }
    }
    __syncthreads();
    {
        int h4 = t & 31, jg = t >> 5;
        const float* xp = Xy + (((size_t)b * Nc + js * 128) + jg * 16) * Hc + h4 * 4;
        float* Pb = Pp + (size_t)js * MNc * Hc;
        float4 acc[8];
#pragma unroll
        for (int r = 0; r < 8; ++r) acc[r] = make_float4(0.f, 0.f, 0.f, 0.f);
        float4 xc = *(const float4*)(xp);
        float4 xn = *(const float4*)(xp + Hc);
#pragma unroll 4
        for (int jq = 0; jq < 16; ++jq) {
            float4 x = xc;
            xc = xn;
            if (jq < 14) xn = *(const float4*)(xp + (jq + 2) * Hc);
            int j = jg * 16 + jq;
#pragma unroll
            for (int r = 0; r < 8; ++r) {
                float av = als[r * 128 + j];
                acc[r].x = fmaf(av, x.x, acc[r].x);
                acc[r].y = fmaf(av, x.y, acc[r].y);
                acc[r].z = fmaf(av, x.z, acc[r].z);
                acc[r].w = fmaf(av, x.w, acc[r].w);
            }
        }
#pragma unroll
        for (int r = 0; r < 4; ++r) red4[jg * 128 + r * 32 + h4] = acc[r];
        __syncthreads();
        if (t < 128) {
            int ii = t >> 5, hq = t & 31;
            float4 s = red4[ii * 32 + hq];
#pragma unroll
            for (int gq = 1; gq < 8; ++gq) {
                float4 p = red4[gq * 128 + ii * 32 + hq];
                s.x += p.x; s.y += p.y; s.z += p.z; s.w += p.w;
            }
            *(float4*)(Pb + ((size_t)b * Nc + i0 + ii) * Hc + hq * 4) = s;
        }
        __syncthreads();
#pragma unroll
        for (int r = 0; r < 4; ++r) red4[jg * 128 + r * 32 + h4] = acc[4 + r];
        __syncthreads();
        if (t < 128) {
            int ii = t >> 5, hq = t & 31;
            float4 s = red4[ii * 32 + hq];
#pragma unroll
            for (int gq = 1; gq < 8; ++gq) {
                float4 p = red4[gq * 128 + ii * 32 + hq];
                s.x += p.x; s.y += p.y; s.z += p.z; s.w += p.w;
            }
            *(float4*)(Pb + ((size_t)b * Nc + i0 + 4 + ii) * Hc + hq * 4) = s;
        }
    }
}

// Combine the 4 j-quarters + SE partial; GS = GS1 + GS2 (frozen from r16).
__global__ __launch_bounds__(256) void combine_se(
        const float* __restrict__ Pp, const float* __restrict__ ctxp,
        const float* __restrict__ wsp, const float* __restrict__ we_w,
        const float* __restrict__ we_b, const float* __restrict__ GS1,
        const float* __restrict__ GS2,
        float* __restrict__ Xbar, float* __restrict__ part) {
    int blk = blockIdx.x;
    int m0 = blk * 8;
    int t = threadIdx.x;
    __shared__ float ctxs[8 * 32];
    __shared__ float sinv[8];
    __shared__ float4 sred[256];
    if (t < 8) {
        float ws = 0.f;
#pragma unroll
        for (int s = 0; s < 4; ++s) ws += wsp[(size_t)s * MNc + m0 + t];
        sinv[t] = 4.f / ws;
    }
    {
        float c = 0.f;
#pragma unroll
        for (int s = 0; s < 4; ++s) c += ctxp[((size_t)s * MNc + m0) * 32 + t];
        ctxs[t] = c;
    }
    __syncthreads();
    int ii = t >> 5, hq = t & 31;
    size_t o = (size_t)(m0 + ii) * Hc + hq * 4;
    float4 ps = *(const float4*)(Pp + o);
#pragma unroll
    for (int s = 1; s < 4; ++s) {
        float4 p = *(const float4*)(Pp + (size_t)s * MNc * Hc + o);
        ps.x += p.x; ps.y += p.y; ps.z += p.z; ps.w += p.w;
    }
    float si = sinv[ii];
    const float* c = ctxs + ii * 32;
    float wec[4];
#pragma unroll
    for (int ho_ = 0; ho_ < 4; ++ho_) {
        const float4* wrow = (const float4*)(we_w + (size_t)(hq * 4 + ho_) * 32);
        float sv = 0.f;
#pragma unroll
        for (int q = 0; q < 8; ++q) {
            float4 w4 = wrow[q];
            sv = fmaf(w4.x, c[4 * q], sv); sv = fmaf(w4.y, c[4 * q + 1], sv);
            sv = fmaf(w4.z, c[4 * q + 2], sv); sv = fmaf(w4.w, c[4 * q + 3], sv);
        }
        wec[ho_] = sv;
    }
    float4 wb = *(const float4*)(we_b + hq * 4);
    float4 g1 = *(const float4*)(GS1 + o);
    float4 g2 = *(const float4*)(GS2 + o);
    float4 outv;
    outv.x = (ps.x + wec[0]) * si + wb.x + g1.x + g2.x;
    outv.y = (ps.y + wec[1]) * si + wb.y + g1.y + g2.y;
    outv.z = (ps.z + wec[2]) * si + wb.z + g1.z + g2.z;
    outv.w = (ps.w + wec[3]) * si + wb.w + g1.w + g2.w;
    *(float4*)(Xbar + o) = outv;
    sred[ii * 32 + hq] = outv;
    __syncthreads();
    if (t < 32) {
        float4 s0 = sred[t];
#pragma unroll
        for (int g = 1; g < 8; ++g) {
            float4 p = sred[g * 32 + t];
            s0.x += p.x; s0.y += p.y; s0.z += p.z; s0.w += p.w;
        }
        *(float4*)(part + (size_t)blk * Hc + t * 4) = s0;
    }
}

// MLP GEMM, register-tiled: 32 rows/block, grid 128. In-block SE gate
// (y2 recomputed from part, ~16K FLOP). LAST=1 runs the head in-block.
template <int LAST>
__global__ __launch_bounds__(256) void mlp_gemm4(
        const float* __restrict__ Xbar, const float* __restrict__ W,
        const float* __restrict__ bias, const float* __restrict__ part,
        const float* __restrict__ l1w, const float* __restrict__ l1b,
        const float* __restrict__ l2w, const float* __restrict__ l2b,
        float* __restrict__ Y,
        const float* __restrict__ h1w, const float* __restrict__ h1b,
        const float* __restrict__ h2w, const float* __restrict__ h2b,
        float* __restrict__ out) {
    __shared__ float xs[32 * Hc];     // 16 KB
    __shared__ float Ws[Hc * WPAD];   // 18 KB
    __shared__ float s[Hc];
    __shared__ float y1s[REDc];
    __shared__ float y2s[Hc];
    int m0 = blockIdx.x * 32;
    int b = m0 >> 9;
    int t = threadIdx.x;
    {
        const float4* src = (const float4*)(Xbar + (size_t)m0 * Hc);
#pragma unroll
        for (int i = 0; i < 4; ++i) ((float4*)xs)[t + i * 256] = src[t + i * 256];
    }
    if (t < 128) {
        const float* pb = part + (size_t)b * 64 * Hc;
        float acc = 0.f;
        for (int p = 0; p < 64; ++p) acc += pb[p * Hc + t];
        s[t] = acc;
    }
    __syncthreads();
    if (t < REDc) {
        float a = l1b[t];
        const float* w = l1w + (size_t)t * Hc;
        for (int k = 0; k < Hc; ++k) a = fmaf(s[k], w[k], a);
        y1s[t] = fmaxf(a, 0.f);
    }
    __syncthreads();
    if (t < 128) {
        float a = l2b[t];
        const float* w2 = l2w + (size_t)t * REDc;
#pragma unroll
        for (int k = 0; k < REDc; ++k) a = fmaf(y1s[k], w2[k], a);
        y2s[t] = 1.f / (1.f + __expf(-a));
    }
    __syncthreads();
    // gate the staged tile: 1024 float4s, y2 index = (float4 idx) & 31
    {
#pragma unroll
        for (int i = 0; i < 4; ++i) {
            int idx = t + i * 256;
            float4 yv = ((const float4*)y2s)[idx & 31];
            float4 v = ((float4*)xs)[idx];
            v.x *= yv.x; v.y *= yv.y; v.z *= yv.z; v.w *= yv.w;
            ((float4*)xs)[idx] = v;
        }
    }
    int cg = t & 31, rg = t >> 5;
    float acc[4][4];
#pragma unroll
    for (int r = 0; r < 4; ++r)
#pragma unroll
        for (int c = 0; c < 4; ++c) acc[r][c] = 0.f;
#pragma unroll 1
    for (int kt = 0; kt < Hc; kt += KT) {
        __syncthreads();              // covers gate write on first iter
        stage_wtile(W, kt, Ws, t);
        __syncthreads();
#pragma unroll
        for (int k = 0; k < KT; k += 4) {
            float4 xv[4], wv[4];
#pragma unroll
            for (int r = 0; r < 4; ++r)
                xv[r] = *(const float4*)(xs + (rg * 4 + r) * Hc + kt + k);
#pragma unroll
            for (int c = 0; c < 4; ++c)
                wv[c] = *(const float4*)(Ws + (cg + 32 * c) * WPAD + k);
#pragma unroll
            for (int r = 0; r < 4; ++r)
#pragma unroll
                for (int c = 0; c < 4; ++c) {
                    acc[r][c] = fmaf(xv[r].x, wv[c].x, acc[r][c]);
                    acc[r][c] = fmaf(xv[r].y, wv[c].y, acc[r][c]);
                    acc[r][c] = fmaf(xv[r].z, wv[c].z, acc[r][c]);
                    acc[r][c] = fmaf(xv[r].w, wv[c].w, acc[r][c]);
                }
        }
    }
    float bvv[4];
#pragma unroll
    for (int c = 0; c < 4; ++c) bvv[c] = bias[cg + 32 * c];
    if (!LAST) {
#pragma unroll
        for (int r = 0; r < 4; ++r)
#pragma unroll
            for (int c = 0; c < 4; ++c)
                Y[(size_t)(m0 + rg * 4 + r) * Hc + cg + 32 * c] = acc[r][c] + bvv[c];
    } else {
        // stage MLP result into xs, then head in-block (hs reuses Ws LDS)
        float* hs = Ws;               // 32*64 floats = 8 KB, fits in Ws
        __syncthreads();
#pragma unroll
        for (int r = 0; r < 4; ++r)
#pragma unroll
            for (int c = 0; c < 4; ++c)
                xs[(rg * 4 + r) * Hc + cg + 32 * c] = acc[r][c] + bvv[c];
        __syncthreads();
        {
            int n2 = t & 63, g2 = t >> 6;    // 4 groups x 8 rows
            float a[8];
            const float* wh = h1w + (size_t)n2 * Hc;
            float bh = h1b[n2];
#pragma unroll
            for (int r = 0; r < 8; ++r) a[r] = bh;
            for (int k = 0; k < Hc; k += 4) {
                float4 wv = *(const float4*)(wh + k);
#pragma unroll
                for (int r = 0; r < 8; ++r) {
                    float4 xv = *(const float4*)(xs + (g2 * 8 + r) * Hc + k);
                    a[r] = fmaf(xv.x, wv.x, a[r]); a[r] = fmaf(xv.y, wv.y, a[r]);
                    a[r] = fmaf(xv.z, wv.z, a[r]); a[r] = fmaf(xv.w, wv.w, a[r]);
                }
            }
#pragma unroll
            for (int r = 0; r < 8; ++r)
                hs[(g2 * 8 + r) * 64 + n2] = fmaxf(a[r], 0.f);
        }
        __syncthreads();
        if (t < 32 * OUTc) {
            int m = t / OUTc, o = t - m * OUTc;
            float a = h2b[o];
            const float* w2 = h2w + (size_t)o * 64;
            const float* hr = hs + m * 64;
#pragma unroll
            for (int k = 0; k < 64; ++k) a = fmaf(hr[k], w2[k], a);
            out[(size_t)(m0 + m) * OUTc + o] = a;
        }
    }
}

extern "C" void kernel_launch(void* const* d_in, const int* in_sizes, int n_in,
                              void* d_out, int out_size, void* d_ws, size_t ws_size,
                              hipStream_t stream) {
    const float* X       = (const float*)d_in[0];
    const float* A       = (const float*)d_in[1];
    const float* Acg     = (const float*)d_in[2];
    const float* embed_w = (const float*)d_in[3];
    const float* embed_b = (const float*)d_in[4];
    const float* topo_eps= (const float*)d_in[5];
    const float* topo_w  = (const float*)d_in[6];
    const float* topo_b  = (const float*)d_in[7];
    const float* theta   = (const float*)d_in[8];
    const float* gin_eps = (const float*)d_in[9];
    const float* gin_w   = (const float*)d_in[10];
    const float* gin_b   = (const float*)d_in[11];
    const float* wo      = (const float*)d_in[12];
    const float* w1      = (const float*)d_in[13];
    const float* wphi    = (const float*)d_in[14];
    const float* wy_w    = (const float*)d_in[15];
    const float* wy_b    = (const float*)d_in[16];
    const float* we_w    = (const float*)d_in[17];
    const float* we_b    = (const float*)d_in[18];
    const float* lin1_w  = (const float*)d_in[19];
    const float* lin1_b  = (const float*)d_in[20];
    const float* lin2_w  = (const float*)d_in[21];
    const float* lin2_b  = (const float*)d_in[22];
    const float* mlp_w   = (const float*)d_in[23];
    const float* mlp_b   = (const float*)d_in[24];
    const float* head1_w = (const float*)d_in[25];
    const float* head1_b = (const float*)d_in[26];
    const float* head2_w = (const float*)d_in[27];
    const float* head2_b = (const float*)d_in[28];
    float* out = (float*)d_out;

    float* ws = (float*)d_ws;
    const int MN = Bc * Nc;              // 4096
    const size_t SZ = (size_t)MN * Hc;   // 524288
    float* Xh   = ws;
    float* Xp   = Xh + SZ;
    float* T1   = Xp + SZ;
    float* T2   = T1 + SZ;
    float* GS1  = T2 + SZ;
    float* GS2  = GS1 + SZ;
    float* Xy   = GS2 + SZ;
    float* hov  = Xy + SZ;
    float* h1v  = hov + (size_t)MN * Atc;
    float* part = h1v + (size_t)MN * Atc;        // MN/8 * Hc
    float* Pp   = part + (size_t)(MN / 8) * Hc;  // 4 * SZ
    float* ctxp = Pp + 4 * SZ;                   // 4 * MN * 32
    float* wsp  = ctxp + (size_t)4 * MN * Atc;   // 4 * MN
    int* idxA   = (int*)(wsp + (size_t)4 * MN);  // MN * 512 ints
    int* idxC   = idxA + (size_t)MN * Nc;
    int* cntA   = idxC + (size_t)MN * Nc;
    int* cntC   = cntA + MN;
    float* Xbar = T1;                    // alias: T1 dead after layer_gemm4

    prologue<<<MN + MN / 8, 256, 0, stream>>>(A, Acg, idxA, idxC, cntA, cntC,
                                              X, embed_w, embed_b, Xh);
    spmm_pre<<<MN, 128, 0, stream>>>(idxA, idxC, cntA, cntC, Xh, topo_eps, topo_eps, T1, T2);
    topo_gemm4<<<MN / 32, 256, 0, stream>>>(T1, T2, topo_w, topo_b, Xh, theta, Xp);

    for (int l = 0; l < Lc; ++l) {
        spmm_pre<<<MN, 128, 0, stream>>>(idxA, idxC, cntA, cntC, Xp,
                                         gin_eps + l * 2, gin_eps + l * 2 + 1, T1, T2);
        layer_gemm4<<<4 * (MN / 32), 256, 0, stream>>>(T1, T2,
            gin_w + (size_t)(l * 2 + 0) * Hc * Hc, gin_b + (size_t)(l * 2 + 0) * Hc,
            gin_w + (size_t)(l * 2 + 1) * Hc * Hc, gin_b + (size_t)(l * 2 + 1) * Hc,
            Xp, wy_w + (size_t)l * Hc * Hc, wy_b + (size_t)l * Hc,
            wo + (size_t)l * Atc * Hc, w1 + (size_t)l * Atc * Hc,
            GS1, GS2, Xy, hov, h1v);
        attn_part<<<MN / 2, 256, 0, stream>>>(hov, h1v, wphi + (size_t)l * Atc, Xy,
                                              Pp, ctxp, wsp);
        combine_se<<<MN / 8, 256, 0, stream>>>(Pp, ctxp, wsp,
                                               we_w + (size_t)l * Hc * Atc,
                                               we_b + (size_t)l * Hc, GS1, GS2, Xbar, part);
        if (l < Lc - 1) {
            mlp_gemm4<0><<<MN / 32, 256, 0, stream>>>(Xbar, mlp_w + (size_t)l * Hc * Hc,
                mlp_b + (size_t)l * Hc, part,
                lin1_w + (size_t)l * REDc * Hc, lin1_b + (size_t)l * REDc,
                lin2_w + (size_t)l * Hc * REDc, lin2_b + (size_t)l * Hc,
                Xp, head1_w, head1_b, head2_w, head2_b, out);
        } else {
            mlp_gemm4<1><<<MN / 32, 256, 0, stream>>>(Xbar, mlp_w + (size_t)l * Hc * Hc,
                mlp_b + (size_t)l * Hc, part,
                lin1_w + (size_t)l * REDc * Hc, lin1_b + (size_t)l * REDc,
                lin2_w + (size_t)l * Hc * REDc, lin2_b + (size_t)l * Hc,
                Xp, head1_w, head1_b, head2_w, head2_b, out);
        }
    }
}

// Round 18
// 375.613 us; speedup vs baseline: 1.0117x; 1.0117x over previous
//
#include <hip/hip_runtime.h>

#define Bc 8
#define Nc 512
#define INc 64
#define Hc 128
#define Atc 32
#define REDc 32
#define OUTc 3
#define Lc 3
#define MNc (Bc * Nc)
#define KT 32
#define WPAD 36   // row stride 144B: conflict-free strided b128 reads

__device__ __forceinline__ float tanh_fast(float x) {
    float e = __expf(2.f * x);
    return 1.f - 2.f * __builtin_amdgcn_rcpf(e + 1.f);
}

// Prologue: blocks [0, MN) build CSR; blocks [MN, MN+MN/8) run embed GEMM.
__global__ __launch_bounds__(256) void prologue(
        const float* __restrict__ A, const float* __restrict__ Acg,
        int* __restrict__ idxA, int* __restrict__ idxC,
        int* __restrict__ cntA, int* __restrict__ cntC,
        const float* __restrict__ X, const float* __restrict__ embed_w,
        const float* __restrict__ embed_b, float* __restrict__ Xh) {
    __shared__ int cA, cC;
    __shared__ float xs[8 * INc];
    int blk = blockIdx.x;
    int t = threadIdx.x;
    if (blk < MNc) {
        if (t == 0) { cA = 0; cC = 0; }
        __syncthreads();
        if (t < 128) {
            int h = t;
            int* ia = idxA + (size_t)blk * Nc;
            int* ic = idxC + (size_t)blk * Nc;
            float4 a4 = ((const float4*)(A + (size_t)blk * Nc))[h];
            if (a4.x != 0.f) ia[atomicAdd(&cA, 1)] = 4 * h;
            if (a4.y != 0.f) ia[atomicAdd(&cA, 1)] = 4 * h + 1;
            if (a4.z != 0.f) ia[atomicAdd(&cA, 1)] = 4 * h + 2;
            if (a4.w != 0.f) ia[atomicAdd(&cA, 1)] = 4 * h + 3;
            float4 c4 = ((const float4*)(Acg + (size_t)blk * Nc))[h];
            if (c4.x != 0.f) ic[atomicAdd(&cC, 1)] = 4 * h;
            if (c4.y != 0.f) ic[atomicAdd(&cC, 1)] = 4 * h + 1;
            if (c4.z != 0.f) ic[atomicAdd(&cC, 1)] = 4 * h + 2;
            if (c4.w != 0.f) ic[atomicAdd(&cC, 1)] = 4 * h + 3;
        }
        __syncthreads();
        if (t == 0) { cntA[blk] = cA; cntC[blk] = cC; }
    } else {
        int m0 = (blk - MNc) * 8;
        if (t < 128) ((float4*)xs)[t] = ((const float4*)(X + (size_t)m0 * INc))[t];
        __syncthreads();
        int n = t & 127, grp = t >> 7;
        float bv = embed_b[n];
        float acc[4];
#pragma unroll
        for (int r = 0; r < 4; ++r) acc[r] = bv;
        const float* w = embed_w + (size_t)n * INc;
        for (int k = 0; k < INc; k += 4) {
            float4 wv = *(const float4*)(w + k);
#pragma unroll
            for (int r = 0; r < 4; ++r) {
                float4 xv = *(const float4*)(xs + (grp * 4 + r) * INc + k);
                acc[r] = fmaf(xv.x, wv.x, acc[r]); acc[r] = fmaf(xv.y, wv.y, acc[r]);
                acc[r] = fmaf(xv.z, wv.z, acc[r]); acc[r] = fmaf(xv.w, wv.w, acc[r]);
            }
        }
#pragma unroll
        for (int r = 0; r < 4; ++r)
            Xh[(size_t)(m0 + grp * 4 + r) * Hc + n] = acc[r];
    }
}

// Dual SpMM from precomputed CSR. WIDE grid — gather latency hidden by TLP.
__global__ __launch_bounds__(128) void spmm_pre(
        const int* __restrict__ idxA, const int* __restrict__ idxC,
        const int* __restrict__ cntA, const int* __restrict__ cntC,
        const float* __restrict__ X, const float* __restrict__ eA,
        const float* __restrict__ eC, float* __restrict__ T1, float* __restrict__ T2) {
    int bi = blockIdx.x;
    int b = bi >> 9;
    int h = threadIdx.x;
    __shared__ int ias[Nc], ics[Nc];
    int nA = cntA[bi], nC = cntC[bi];
    for (int q = h; q < nA; q += 128) ias[q] = idxA[(size_t)bi * Nc + q];
    for (int q = h; q < nC; q += 128) ics[q] = idxC[(size_t)bi * Nc + q];
    __syncthreads();
    const float* Xb = X + (size_t)b * Nc * Hc;
    float a1 = 0.f, a2 = 0.f;
    for (int q = 0; q < nA; ++q) a1 += Xb[(size_t)ias[q] * Hc + h];
    for (int q = 0; q < nC; ++q) a2 += Xb[(size_t)ics[q] * Hc + h];
    size_t o = (size_t)bi * Hc + h;
    float xv = X[o];
    T1[o] = (1.f + eA[0]) * xv + a1;
    T2[o] = (1.f + eC[0]) * xv + a2;
}

// Topo dual GIN + combine (r16 form, 8 rows/block — runs once; neutral vs
// register-tiled port per r17 A/B, so keep the longer-verified version).
__global__ __launch_bounds__(256) void gemm2_topo(
        const float* __restrict__ T1, const float* __restrict__ T2,
        const float* __restrict__ W, const float* __restrict__ bias,
        const float* __restrict__ Xh, const float* __restrict__ theta,
        float* __restrict__ Xp) {
    __shared__ float xs1[8 * Hc], xs2[8 * Hc];
    int m0 = blockIdx.x * 8;
    int t = threadIdx.x;
    for (int idx4 = t; idx4 < 8 * Hc / 4; idx4 += 256) {
        ((float4*)xs1)[idx4] = ((const float4*)(T1 + (size_t)m0 * Hc))[idx4];
        ((float4*)xs2)[idx4] = ((const float4*)(T2 + (size_t)m0 * Hc))[idx4];
    }
    __syncthreads();
    int n = t & 127, grp = t >> 7;
    float bv = bias[n];
    float ac1[4], ac2[4];
#pragma unroll
    for (int r = 0; r < 4; ++r) { ac1[r] = bv; ac2[r] = bv; }
    const float* w = W + (size_t)n * Hc;
    for (int k = 0; k < Hc; k += 4) {
        float4 wv = *(const float4*)(w + k);
#pragma unroll
        for (int r = 0; r < 4; ++r) {
            float4 x1 = *(const float4*)(xs1 + (grp * 4 + r) * Hc + k);
            float4 x2 = *(const float4*)(xs2 + (grp * 4 + r) * Hc + k);
            ac1[r] = fmaf(x1.x, wv.x, ac1[r]); ac1[r] = fmaf(x1.y, wv.y, ac1[r]);
            ac1[r] = fmaf(x1.z, wv.z, ac1[r]); ac1[r] = fmaf(x1.w, wv.w, ac1[r]);
            ac2[r] = fmaf(x2.x, wv.x, ac2[r]); ac2[r] = fmaf(x2.y, wv.y, ac2[r]);
            ac2[r] = fmaf(x2.z, wv.z, ac2[r]); ac2[r] = fmaf(x2.w, wv.w, ac2[r]);
        }
    }
    float th0 = theta[2 * n], th1 = theta[2 * n + 1];
#pragma unroll
    for (int r = 0; r < 4; ++r) {
        size_t o = (size_t)(m0 + grp * 4 + r) * Hc + n;
        float g1 = fmaxf(ac1[r], 0.f), g2 = fmaxf(ac2[r], 0.f);
        Xp[o] = Xh[o] + tanh_fast(g1 * th0) + tanh_fast(g2 * th1);
    }
}

// Stage one KT-wide weight tile into Ws[128][WPAD] (coalesced global reads).
__device__ __forceinline__ void stage_wtile(
        const float* __restrict__ W, int kt, float* Ws, int t) {
#pragma unroll
    for (int i = 0; i < 4; ++i) {
        int idx = t + i * 256;
        int row = idx >> 3, c4 = idx & 7;
        float4 v = *(const float4*)(W + (size_t)row * Hc + kt + c4 * 4);
        *(float4*)(Ws + row * WPAD + c4 * 4) = v;
    }
}

// 8-row GEMM helper with LDS-staged weights (for mlp_gemm).
__device__ __forceinline__ void gemm_lds(
        const float* __restrict__ W, const float* xsrc, float* Ws,
        int n, int grp, int t, float acc[4]) {
#pragma unroll 1
    for (int kt = 0; kt < Hc; kt += KT) {
        __syncthreads();
        stage_wtile(W, kt, Ws, t);
        __syncthreads();
#pragma unroll
        for (int k = 0; k < KT; k += 4) {
            float4 wv = *(const float4*)(Ws + n * WPAD + k);
#pragma unroll
            for (int r = 0; r < 4; ++r) {
                float4 xv = *(const float4*)(xsrc + (grp * 4 + r) * Hc + kt + k);
                acc[r] = fmaf(xv.x, wv.x, acc[r]); acc[r] = fmaf(xv.y, wv.y, acc[r]);
                acc[r] = fmaf(xv.z, wv.z, acc[r]); acc[r] = fmaf(xv.w, wv.w, acc[r]);
            }
        }
    }
}

// Per-layer GEMMs, register-tiled (r16 WIN, −61.5us): 4 roles x 128 blocks,
// 32 rows/block, 4x4 thread tile -> 8 ds_read_b128 per 64 FMAs (VALU-bound;
// the r15 8-row form was LDS-instruction-throughput bound at 5 b128/16 FMA).
__global__ __launch_bounds__(256) void layer_gemm4(
        const float* __restrict__ T1, const float* __restrict__ T2,
        const float* __restrict__ W1, const float* __restrict__ b1,
        const float* __restrict__ W2, const float* __restrict__ b2,
        const float* __restrict__ Xp, const float* __restrict__ wy_w,
        const float* __restrict__ wy_b, const float* __restrict__ wo,
        const float* __restrict__ w1a, float* __restrict__ GS1,
        float* __restrict__ GS2, float* __restrict__ Xy,
        float* __restrict__ hov, float* __restrict__ h1v) {
    __shared__ float xs[32 * Hc];     // 16 KB
    __shared__ float Ws[Hc * WPAD];   // 18 KB
    int blk = blockIdx.x;
    int role = blk >> 7;
    int m0 = (blk & 127) * 32;
    int t = threadIdx.x;
    const float* xsrc = (role == 0) ? T1 : (role == 1) ? T2 : Xp;
    {
        const float4* src = (const float4*)(xsrc + (size_t)m0 * Hc);
#pragma unroll
        for (int i = 0; i < 4; ++i) ((float4*)xs)[t + i * 256] = src[t + i * 256];
    }
    if (role == 3) {
        __syncthreads();
        int n2 = t & 63, g2 = t >> 6;
        const float* w = (n2 < 32) ? (wo + (size_t)n2 * Hc) : (w1a + (size_t)(n2 - 32) * Hc);
        float acc[8];
#pragma unroll
        for (int r = 0; r < 8; ++r) acc[r] = 0.f;
        for (int k = 0; k < Hc; k += 4) {
            float4 wv = *(const float4*)(w + k);
#pragma unroll
            for (int r = 0; r < 8; ++r) {
                float4 xv = *(const float4*)(xs + (g2 * 8 + r) * Hc + k);
                acc[r] = fmaf(xv.x, wv.x, acc[r]); acc[r] = fmaf(xv.y, wv.y, acc[r]);
                acc[r] = fmaf(xv.z, wv.z, acc[r]); acc[r] = fmaf(xv.w, wv.w, acc[r]);
            }
        }
#pragma unroll
        for (int r = 0; r < 8; ++r) {
            int m = m0 + g2 * 8 + r;
            float v = tanh_fast(acc[r]);
            if (n2 < 32) hov[(size_t)m * Atc + n2] = v;
            else h1v[(size_t)m * Atc + (n2 - 32)] = v;
        }
        return;
    }
    const float* W = (role == 0) ? W1 : (role == 1) ? W2 : wy_w;
    const float* bias = (role == 0) ? b1 : (role == 1) ? b2 : wy_b;
    int cg = t & 31, rg = t >> 5;
    float acc[4][4];
#pragma unroll
    for (int r = 0; r < 4; ++r)
#pragma unroll
        for (int c = 0; c < 4; ++c) acc[r][c] = 0.f;
#pragma unroll 1
    for (int kt = 0; kt < Hc; kt += KT) {
        __syncthreads();
        stage_wtile(W, kt, Ws, t);
        __syncthreads();
#pragma unroll
        for (int k = 0; k < KT; k += 4) {
            float4 xv[4], wv[4];
#pragma unroll
            for (int r = 0; r < 4; ++r)
                xv[r] = *(const float4*)(xs + (rg * 4 + r) * Hc + kt + k);
#pragma unroll
            for (int c = 0; c < 4; ++c)
                wv[c] = *(const float4*)(Ws + (cg + 32 * c) * WPAD + k);
#pragma unroll
            for (int r = 0; r < 4; ++r)
#pragma unroll
                for (int c = 0; c < 4; ++c) {
                    acc[r][c] = fmaf(xv[r].x, wv[c].x, acc[r][c]);
                    acc[r][c] = fmaf(xv[r].y, wv[c].y, acc[r][c]);
                    acc[r][c] = fmaf(xv[r].z, wv[c].z, acc[r][c]);
                    acc[r][c] = fmaf(xv[r].w, wv[c].w, acc[r][c]);
                }
        }
    }
    float bvv[4];
#pragma unroll
    for (int c = 0; c < 4; ++c) bvv[c] = bias[cg + 32 * c];
    if (role == 0) {
#pragma unroll
        for (int r = 0; r < 4; ++r)
#pragma unroll
            for (int c = 0; c < 4; ++c)
                GS1[(size_t)(m0 + rg * 4 + r) * Hc + cg + 32 * c] =
                    fmaxf(acc[r][c] + bvv[c], 0.f);
    } else if (role == 1) {
#pragma unroll
        for (int r = 0; r < 4; ++r)
#pragma unroll
            for (int c = 0; c < 4; ++c)
                GS2[(size_t)(m0 + rg * 4 + r) * Hc + cg + 32 * c] =
                    fmaxf(acc[r][c] + bvv[c], 0.f);
    } else {
#pragma unroll
        for (int r = 0; r < 4; ++r)
#pragma unroll
            for (int c = 0; c < 4; ++c)
                Xy[(size_t)(m0 + rg * 4 + r) * Hc + cg + 32 * c] = acc[r][c] + bvv[c];
    }
}

// Flash-style partial attention (frozen since r13; structural floor per r5-r7).
__global__ __launch_bounds__(256, 4) void attn_part(
        const float* __restrict__ ta, const float* __restrict__ tb,
        const float* __restrict__ wphi, const float* __restrict__ Xy,
        float* __restrict__ Pp, float* __restrict__ ctxp, float* __restrict__ wsp) {
    int blk = blockIdx.x;
    int b = blk >> 8;
    int r6 = (blk >> 2) & 63;
    int js = blk & 3;
    int i0 = r6 * 8;
    int t = threadIdx.x;
    __shared__ float als[8 * 128];
    __shared__ float4 red4[1024];
    __shared__ float tas[8 * 32];
    tas[t] = ta[((size_t)b * Nc + i0) * 32 + t];
    __syncthreads();
    {
        int i = t >> 5;
        int kq = t & 3;
        int jl = (t >> 2) & 7;
        float4 wp0 = ((const float4*)wphi)[kq * 2];
        float4 wp1 = ((const float4*)wphi)[kq * 2 + 1];
        float4 ta0 = *(const float4*)(tas + i * 32 + kq * 8);
        float4 ta1 = *(const float4*)(tas + i * 32 + kq * 8 + 4);
        const float* tbb = tb + ((size_t)b * Nc + js * 128) * 32;
        const float4* p = (const float4*)(tbb + (size_t)jl * 32 + kq * 8);
        float4 c0a = p[0], c0b = p[1];
        float4 c1a = p[64], c1b = p[65];
        float ca[8];
#pragma unroll
        for (int q = 0; q < 8; ++q) ca[q] = 0.f;
        float wsum = 0.f;
#pragma unroll 4
        for (int jj = 0; jj < 16; ++jj) {
            float4 ha = c0a, hb = c0b;
            c0a = c1a; c0b = c1b;
            if (jj < 14) { c1a = p[(jj + 2) * 64]; c1b = p[(jj + 2) * 64 + 1]; }
            float e0 = (ta0.x + ha.x) * __builtin_amdgcn_rcpf(fmaf(ta0.x, ha.x, 1.f));
            float e1 = (ta0.y + ha.y) * __builtin_amdgcn_rcpf(fmaf(ta0.y, ha.y, 1.f));
            float e2 = (ta0.z + ha.z) * __builtin_amdgcn_rcpf(fmaf(ta0.z, ha.z, 1.f));
            float e3 = (ta0.w + ha.w) * __builtin_amdgcn_rcpf(fmaf(ta0.w, ha.w, 1.f));
            float e4 = (ta1.x + hb.x) * __builtin_amdgcn_rcpf(fmaf(ta1.x, hb.x, 1.f));
            float e5 = (ta1.y + hb.y) * __builtin_amdgcn_rcpf(fmaf(ta1.y, hb.y, 1.f));
            float e6 = (ta1.z + hb.z) * __builtin_amdgcn_rcpf(fmaf(ta1.z, hb.z, 1.f));
            float e7 = (ta1.w + hb.w) * __builtin_amdgcn_rcpf(fmaf(ta1.w, hb.w, 1.f));
            float s01 = fmaf(e1, wp0.y, e0 * wp0.x);
            float s23 = fmaf(e3, wp0.w, e2 * wp0.z);
            float s45 = fmaf(e5, wp1.y, e4 * wp1.x);
            float s67 = fmaf(e7, wp1.w, e6 * wp1.z);
            float sc = (s01 + s23) + (s45 + s67);
            sc += __shfl_xor(sc, 1);
            sc += __shfl_xor(sc, 2);
            float w = __expf(sc);
            if (kq == 0) als[i * 128 + jj * 8 + jl] = w;
            wsum += w;
            ca[0] = fmaf(w, e0, ca[0]);
            ca[1] = fmaf(w, e1, ca[1]);
            ca[2] = fmaf(w, e2, ca[2]);
            ca[3] = fmaf(w, e3, ca[3]);
            ca[4] = fmaf(w, e4, ca[4]);
            ca[5] = fmaf(w, e5, ca[5]);
            ca[6] = fmaf(w, e6, ca[6]);
            ca[7] = fmaf(w, e7, ca[7]);
        }
#pragma unroll
        for (int o = 16; o > 0; o >>= 1) wsum += __shfl_xor(wsum, o);
        if ((t & 31) == 0) wsp[(size_t)js * MNc + (size_t)b * Nc + i0 + i] = wsum;
#pragma unroll
        for (int q = 0; q < 8; ++q) {
            ca[q] += __shfl_xor(ca[q], 4);
            ca[q] += __shfl_xor(ca[q], 8);
            ca[q] += __shfl_xor(ca[q], 16);
        }
        if (jl == 0) {
            float* cp = ctxp + ((size_t)js * MNc + (size_t)b * Nc + i0 + i) * 32 + kq * 8;
#pragma unroll
            for (int q = 0; q < 8; ++q) cp[q] = ca[q];
        }
    }
    __syncthreads();
    {
        int h4 = t & 31, jg = t >> 5;
        const float* xp = Xy + (((size_t)b * Nc + js * 128) + jg * 16) * Hc + h4 * 4;
        float* Pb = Pp + (size_t)js * MNc * Hc;
        float4 acc[8];
#pragma unroll
        for (int r = 0; r < 8; ++r) acc[r] = make_float4(0.f, 0.f, 0.f, 0.f);
        float4 xc = *(const float4*)(xp);
        float4 xn = *(const float4*)(xp + Hc);
#pragma unroll 4
        for (int jq = 0; jq < 16; ++jq) {
            float4 x = xc;
            xc = xn;
            if (jq < 14) xn = *(const float4*)(xp + (jq + 2) * Hc);
            int j = jg * 16 + jq;
#pragma unroll
            for (int r = 0; r < 8; ++r) {
                float av = als[r * 128 + j];
                acc[r].x = fmaf(av, x.x, acc[r].x);
                acc[r].y = fmaf(av, x.y, acc[r].y);
                acc[r].z = fmaf(av, x.z, acc[r].z);
                acc[r].w = fmaf(av, x.w, acc[r].w);
            }
        }
#pragma unroll
        for (int r = 0; r < 4; ++r) red4[jg * 128 + r * 32 + h4] = acc[r];
        __syncthreads();
        if (t < 128) {
            int ii = t >> 5, hq = t & 31;
            float4 s = red4[ii * 32 + hq];
#pragma unroll
            for (int gq = 1; gq < 8; ++gq) {
                float4 p = red4[gq * 128 + ii * 32 + hq];
                s.x += p.x; s.y += p.y; s.z += p.z; s.w += p.w;
            }
            *(float4*)(Pb + ((size_t)b * Nc + i0 + ii) * Hc + hq * 4) = s;
        }
        __syncthreads();
#pragma unroll
        for (int r = 0; r < 4; ++r) red4[jg * 128 + r * 32 + h4] = acc[4 + r];
        __syncthreads();
        if (t < 128) {
            int ii = t >> 5, hq = t & 31;
            float4 s = red4[ii * 32 + hq];
#pragma unroll
            for (int gq = 1; gq < 8; ++gq) {
                float4 p = red4[gq * 128 + ii * 32 + hq];
                s.x += p.x; s.y += p.y; s.z += p.z; s.w += p.w;
            }
            *(float4*)(Pb + ((size_t)b * Nc + i0 + 4 + ii) * Hc + hq * 4) = s;
        }
    }
}

// Combine the 4 j-quarters + SE partial; GS = GS1 + GS2 (frozen from r16).
__global__ __launch_bounds__(256) void combine_se(
        const float* __restrict__ Pp, const float* __restrict__ ctxp,
        const float* __restrict__ wsp, const float* __restrict__ we_w,
        const float* __restrict__ we_b, const float* __restrict__ GS1,
        const float* __restrict__ GS2,
        float* __restrict__ Xbar, float* __restrict__ part) {
    int blk = blockIdx.x;
    int m0 = blk * 8;
    int t = threadIdx.x;
    __shared__ float ctxs[8 * 32];
    __shared__ float sinv[8];
    __shared__ float4 sred[256];
    if (t < 8) {
        float ws = 0.f;
#pragma unroll
        for (int s = 0; s < 4; ++s) ws += wsp[(size_t)s * MNc + m0 + t];
        sinv[t] = 4.f / ws;
    }
    {
        float c = 0.f;
#pragma unroll
        for (int s = 0; s < 4; ++s) c += ctxp[((size_t)s * MNc + m0) * 32 + t];
        ctxs[t] = c;
    }
    __syncthreads();
    int ii = t >> 5, hq = t & 31;
    size_t o = (size_t)(m0 + ii) * Hc + hq * 4;
    float4 ps = *(const float4*)(Pp + o);
#pragma unroll
    for (int s = 1; s < 4; ++s) {
        float4 p = *(const float4*)(Pp + (size_t)s * MNc * Hc + o);
        ps.x += p.x; ps.y += p.y; ps.z += p.z; ps.w += p.w;
    }
    float si = sinv[ii];
    const float* c = ctxs + ii * 32;
    float wec[4];
#pragma unroll
    for (int ho_ = 0; ho_ < 4; ++ho_) {
        const float4* wrow = (const float4*)(we_w + (size_t)(hq * 4 + ho_) * 32);
        float sv = 0.f;
#pragma unroll
        for (int q = 0; q < 8; ++q) {
            float4 w4 = wrow[q];
            sv = fmaf(w4.x, c[4 * q], sv); sv = fmaf(w4.y, c[4 * q + 1], sv);
            sv = fmaf(w4.z, c[4 * q + 2], sv); sv = fmaf(w4.w, c[4 * q + 3], sv);
        }
        wec[ho_] = sv;
    }
    float4 wb = *(const float4*)(we_b + hq * 4);
    float4 g1 = *(const float4*)(GS1 + o);
    float4 g2 = *(const float4*)(GS2 + o);
    float4 outv;
    outv.x = (ps.x + wec[0]) * si + wb.x + g1.x + g2.x;
    outv.y = (ps.y + wec[1]) * si + wb.y + g1.y + g2.y;
    outv.z = (ps.z + wec[2]) * si + wb.z + g1.z + g2.z;
    outv.w = (ps.w + wec[3]) * si + wb.w + g1.w + g2.w;
    *(float4*)(Xbar + o) = outv;
    sred[ii * 32 + hq] = outv;
    __syncthreads();
    if (t < 32) {
        float4 s0 = sred[t];
#pragma unroll
        for (int g = 1; g < 8; ++g) {
            float4 p = sred[g * 32 + t];
            s0.x += p.x; s0.y += p.y; s0.z += p.z; s0.w += p.w;
        }
        *(float4*)(part + (size_t)blk * Hc + t * 4) = s0;
    }
}

// MLP GEMM with in-block SE gate (r16 form). LAST=1 runs the head in-block.
template <int LAST>
__global__ __launch_bounds__(256) void mlp_gemm(
        const float* __restrict__ Xbar, const float* __restrict__ W,
        const float* __restrict__ bias, const float* __restrict__ part,
        const float* __restrict__ l1w, const float* __restrict__ l1b,
        const float* __restrict__ l2w, const float* __restrict__ l2b,
        float* __restrict__ Y,
        const float* __restrict__ h1w, const float* __restrict__ h1b,
        const float* __restrict__ h2w, const float* __restrict__ h2b,
        float* __restrict__ out) {
    __shared__ float xs[8 * Hc];
    __shared__ float s[Hc];
    __shared__ float y1s[REDc];
    __shared__ float y2s[Hc];
    __shared__ float hs[8 * 64];
    __shared__ float Ws[Hc * WPAD];
    int m0 = blockIdx.x * 8;
    int b = m0 >> 9;
    int t = threadIdx.x;
    ((float4*)xs)[t] = ((const float4*)(Xbar + (size_t)m0 * Hc))[t];
    if (t < 128) {
        const float* pb = part + (size_t)b * 64 * Hc;
        float acc = 0.f;
        for (int p = 0; p < 64; ++p) acc += pb[p * Hc + t];
        s[t] = acc;
    }
    __syncthreads();
    if (t < REDc) {
        float a = l1b[t];
        const float* w = l1w + (size_t)t * Hc;
        for (int k = 0; k < Hc; ++k) a = fmaf(s[k], w[k], a);
        y1s[t] = fmaxf(a, 0.f);
    }
    __syncthreads();
    if (t < 128) {
        float a = l2b[t];
        const float* w2 = l2w + (size_t)t * REDc;
#pragma unroll
        for (int k = 0; k < REDc; ++k) a = fmaf(y1s[k], w2[k], a);
        y2s[t] = 1.f / (1.f + __expf(-a));
    }
    __syncthreads();
    {
        float4 yv = ((const float4*)y2s)[t & 31];
        float4 v = ((float4*)xs)[t];
        v.x *= yv.x; v.y *= yv.y; v.z *= yv.z; v.w *= yv.w;
        ((float4*)xs)[t] = v;
    }
    int n = t & 127, grp = t >> 7;
    float bv = bias[n];
    float acc[4];
#pragma unroll
    for (int r = 0; r < 4; ++r) acc[r] = bv;
    gemm_lds(W, xs, Ws, n, grp, t, acc);
    if (!LAST) {
#pragma unroll
        for (int r = 0; r < 4; ++r)
            Y[(size_t)(m0 + grp * 4 + r) * Hc + n] = acc[r];
    } else {
        __syncthreads();
#pragma unroll
        for (int r = 0; r < 4; ++r) xs[(grp * 4 + r) * Hc + n] = acc[r];
        __syncthreads();
        {
            int n2 = t & 63, g2 = t >> 6;
            float a0 = h1b[n2], a1 = a0;
            const float* wh = h1w + (size_t)n2 * Hc;
            const float* x0 = xs + (g2 * 2) * Hc;
            const float* x1 = xs + (g2 * 2 + 1) * Hc;
            for (int k = 0; k < Hc; k += 4) {
                float4 wv = *(const float4*)(wh + k);
                float4 v0 = *(const float4*)(x0 + k);
                float4 v1 = *(const float4*)(x1 + k);
                a0 = fmaf(v0.x, wv.x, a0); a0 = fmaf(v0.y, wv.y, a0);
                a0 = fmaf(v0.z, wv.z, a0); a0 = fmaf(v0.w, wv.w, a0);
                a1 = fmaf(v1.x, wv.x, a1); a1 = fmaf(v1.y, wv.y, a1);
                a1 = fmaf(v1.z, wv.z, a1); a1 = fmaf(v1.w, wv.w, a1);
            }
            hs[(g2 * 2) * 64 + n2] = fmaxf(a0, 0.f);
            hs[(g2 * 2 + 1) * 64 + n2] = fmaxf(a1, 0.f);
        }
        __syncthreads();
        if (t < 8 * OUTc) {
            int m = t / OUTc, o = t - m * OUTc;
            float a = h2b[o];
            const float* w2 = h2w + (size_t)o * 64;
            const float* hr = hs + m * 64;
#pragma unroll
            for (int k = 0; k < 64; ++k) a = fmaf(hr[k], w2[k], a);
            out[(size_t)(m0 + m) * OUTc + o] = a;
        }
    }
}

extern "C" void kernel_launch(void* const* d_in, const int* in_sizes, int n_in,
                              void* d_out, int out_size, void* d_ws, size_t ws_size,
                              hipStream_t stream) {
    const float* X       = (const float*)d_in[0];
    const float* A       = (const float*)d_in[1];
    const float* Acg     = (const float*)d_in[2];
    const float* embed_w = (const float*)d_in[3];
    const float* embed_b = (const float*)d_in[4];
    const float* topo_eps= (const float*)d_in[5];
    const float* topo_w  = (const float*)d_in[6];
    const float* topo_b  = (const float*)d_in[7];
    const float* theta   = (const float*)d_in[8];
    const float* gin_eps = (const float*)d_in[9];
    const float* gin_w   = (const float*)d_in[10];
    const float* gin_b   = (const float*)d_in[11];
    const float* wo      = (const float*)d_in[12];
    const float* w1      = (const float*)d_in[13];
    const float* wphi    = (const float*)d_in[14];
    const float* wy_w    = (const float*)d_in[15];
    const float* wy_b    = (const float*)d_in[16];
    const float* we_w    = (const float*)d_in[17];
    const float* we_b    = (const float*)d_in[18];
    const float* lin1_w  = (const float*)d_in[19];
    const float* lin1_b  = (const float*)d_in[20];
    const float* lin2_w  = (const float*)d_in[21];
    const float* lin2_b  = (const float*)d_in[22];
    const float* mlp_w   = (const float*)d_in[23];
    const float* mlp_b   = (const float*)d_in[24];
    const float* head1_w = (const float*)d_in[25];
    const float* head1_b = (const float*)d_in[26];
    const float* head2_w = (const float*)d_in[27];
    const float* head2_b = (const float*)d_in[28];
    float* out = (float*)d_out;

    float* ws = (float*)d_ws;
    const int MN = Bc * Nc;              // 4096
    const size_t SZ = (size_t)MN * Hc;   // 524288
    float* Xh   = ws;
    float* Xp   = Xh + SZ;
    float* T1   = Xp + SZ;
    float* T2   = T1 + SZ;
    float* GS1  = T2 + SZ;
    float* GS2  = GS1 + SZ;
    float* Xy   = GS2 + SZ;
    float* hov  = Xy + SZ;
    float* h1v  = hov + (size_t)MN * Atc;
    float* part = h1v + (size_t)MN * Atc;        // MN/8 * Hc
    float* Pp   = part + (size_t)(MN / 8) * Hc;  // 4 * SZ
    float* ctxp = Pp + 4 * SZ;                   // 4 * MN * 32
    float* wsp  = ctxp + (size_t)4 * MN * Atc;   // 4 * MN
    int* idxA   = (int*)(wsp + (size_t)4 * MN);  // MN * 512 ints
    int* idxC   = idxA + (size_t)MN * Nc;
    int* cntA   = idxC + (size_t)MN * Nc;
    int* cntC   = cntA + MN;
    float* Xbar = T1;                    // alias: T1 dead after layer_gemm4

    prologue<<<MN + MN / 8, 256, 0, stream>>>(A, Acg, idxA, idxC, cntA, cntC,
                                              X, embed_w, embed_b, Xh);
    spmm_pre<<<MN, 128, 0, stream>>>(idxA, idxC, cntA, cntC, Xh, topo_eps, topo_eps, T1, T2);
    gemm2_topo<<<MN / 8, 256, 0, stream>>>(T1, T2, topo_w, topo_b, Xh, theta, Xp);

    for (int l = 0; l < Lc; ++l) {
        spmm_pre<<<MN, 128, 0, stream>>>(idxA, idxC, cntA, cntC, Xp,
                                         gin_eps + l * 2, gin_eps + l * 2 + 1, T1, T2);
        layer_gemm4<<<4 * (MN / 32), 256, 0, stream>>>(T1, T2,
            gin_w + (size_t)(l * 2 + 0) * Hc * Hc, gin_b + (size_t)(l * 2 + 0) * Hc,
            gin_w + (size_t)(l * 2 + 1) * Hc * Hc, gin_b + (size_t)(l * 2 + 1) * Hc,
            Xp, wy_w + (size_t)l * Hc * Hc, wy_b + (size_t)l * Hc,
            wo + (size_t)l * Atc * Hc, w1 + (size_t)l * Atc * Hc,
            GS1, GS2, Xy, hov, h1v);
        attn_part<<<MN / 2, 256, 0, stream>>>(hov, h1v, wphi + (size_t)l * Atc, Xy,
                                              Pp, ctxp, wsp);
        combine_se<<<MN / 8, 256, 0, stream>>>(Pp, ctxp, wsp,
                                               we_w + (size_t)l * Hc * Atc,
                                               we_b + (size_t)l * Hc, GS1, GS2, Xbar, part);
        if (l < Lc - 1) {
            mlp_gemm<0><<<MN / 8, 256, 0, stream>>>(Xbar, mlp_w + (size_t)l * Hc * Hc,
                mlp_b + (size_t)l * Hc, part,
                lin1_w + (size_t)l * REDc * Hc, lin1_b + (size_t)l * REDc,
                lin2_w + (size_t)l * Hc * REDc, lin2_b + (size_t)l * Hc,
                Xp, head1_w, head1_b, head2_w, head2_b, out);
        } else {
            mlp_gemm<1><<<MN / 8, 256, 0, stream>>>(Xbar, mlp_w + (size_t)l * Hc * Hc,
                mlp_b + (size_t)l * Hc, part,
                lin1_w + (size_t)l * REDc * Hc, lin1_b + (size_t)l * REDc,
                lin2_w + (size_t)l * Hc * REDc, lin2_b + (size_t)l * Hc,
                Xp, head1_w, head1_b, head2_w, head2_b, out);
        }
    }
}